// Round 11
// baseline (258.763 us; speedup 1.0000x reference)
//
// ===== MaskedAutoencoderViT v11 — OUTPUT DTYPE FIX =====
// Root cause of rounds 1-10: reference outputs are float32, so d_out is
// float* (harness contract), but we wrote packed bf16 shorts. f32 word 0 =
// bf16(pm)<<16 | bf16(loss) ≈ 0.883 -> err 0.9140625, identical every
// round (pm deterministic; low-short probes invisible under bf16-rounded
// comparison). All outputs now float32 at float offsets.
#include <hip/hip_runtime.h>

typedef __attribute__((ext_vector_type(8))) __bf16 bf16x8;
typedef __attribute__((ext_vector_type(4))) float f32x4;
typedef __attribute__((ext_vector_type(4))) unsigned short us4;

typedef const __attribute__((address_space(1))) void* gas;
typedef __attribute__((address_space(3))) void* las;

static __device__ __forceinline__ unsigned short f2bf(float f) {
  unsigned int u = __float_as_uint(f);
  u += 0x7fffu + ((u >> 16) & 1u);
  return (unsigned short)(u >> 16);
}
static __device__ __forceinline__ float bf2f(unsigned short s) {
  return __uint_as_float(((unsigned int)s) << 16);
}

// Block-wide LDS tree reduction over 256 threads, Q quantities; results
// broadcast to all threads.
template <int Q>
__device__ __forceinline__ void btree(float* sm, float* v) {
  const int t = threadIdx.x;
#pragma unroll
  for (int q = 0; q < Q; ++q) sm[q * 256 + t] = v[q];
  __syncthreads();
  for (int o = 128; o > 0; o >>= 1) {
    if (t < o)
#pragma unroll
      for (int q = 0; q < Q; ++q) sm[q * 256 + t] += sm[q * 256 + t + o];
    __syncthreads();
  }
#pragma unroll
  for (int q = 0; q < Q; ++q) v[q] = sm[q * 256];
  __syncthreads();
}

// ---------------- rank_w: stable-sort rank of noise per row ----------------
__global__ __launch_bounds__(512) void rank_w(const float* __restrict__ noise,
                                              int* __restrict__ rank,
                                              int* __restrict__ keep) {
  __shared__ alignas(16) float nz[2000];
  const int b = blockIdx.x;
  const float* nr = noise + b * 2000;
  for (int j = threadIdx.x; j < 2000; j += 512) nz[j] = nr[j];
  __syncthreads();
  const int i = blockIdx.y * 500 + threadIdx.x;
  if (threadIdx.x < 500) {
    const float ni = nz[i];
    int cnt = 0;
#pragma unroll 4
    for (int j4 = 0; j4 < 500; ++j4) {
      float4 v = ((const float4*)nz)[j4];
      const int j = j4 * 4;
      cnt += (int)((v.x < ni) | ((v.x == ni) & (j < i)));
      cnt += (int)((v.y < ni) | ((v.y == ni) & ((j + 1) < i)));
      cnt += (int)((v.z < ni) | ((v.z == ni) & ((j + 2) < i)));
      cnt += (int)((v.w < ni) | ((v.w == ni) & ((j + 3) < i)));
    }
    rank[b * 2000 + i] = cnt;
    if (cnt < 500) keep[b * 500 + cnt] = i;  // dense row index = rank
  }
}

// ---------------- trans_w: W_dec (K x N) -> Bt (N x K) bf16 ----------------
__global__ __launch_bounds__(256) void trans_w(const float* __restrict__ W,
                                               unsigned short* __restrict__ Bt) {
  __shared__ float tile[32][33];
  const int tx = threadIdx.x & 31, ty = threadIdx.x >> 5;  // 32x8
  const int r0 = blockIdx.y * 32, c0 = blockIdx.x * 32;
#pragma unroll
  for (int k = 0; k < 4; ++k)
    tile[ty + k * 8][tx] = W[(size_t)(r0 + ty + k * 8) * 1024 + c0 + tx];
  __syncthreads();
#pragma unroll
  for (int k = 0; k < 4; ++k) {
    const int cr = ty + k * 8;
    Bt[(size_t)(c0 + cr) * 1024 + r0 + tx] = f2bf(tile[tx][cr]);
  }
}

// ------- pre_w: pred_mask = W_pred . LN2(mask_token) + b_pred -------
__global__ __launch_bounds__(256) void pre_w(const float* __restrict__ mtok,
                                             const float* __restrict__ g2,
                                             const float* __restrict__ be2,
                                             const float* __restrict__ Wp,
                                             const float* __restrict__ bp,
                                             float* __restrict__ scal) {
  __shared__ float sm[512];
  const int t = threadIdx.x;
  float4 x = ((const float4*)mtok)[t];
  float v[2];
  v[0] = x.x + x.y + x.z + x.w;
  v[1] = x.x * x.x + x.y * x.y + x.z * x.z + x.w * x.w;
  btree<2>(sm, v);
  const float mean = v[0] * (1.f / 1024.f);
  const float r = rsqrtf(v[1] * (1.f / 1024.f) - mean * mean + 1e-5f);
  float4 g = ((const float4*)g2)[t];
  float4 be = ((const float4*)be2)[t];
  float4 w = ((const float4*)Wp)[t];
  float d[1];
  d[0] = ((x.x - mean) * r * g.x + be.x) * w.x +
         ((x.y - mean) * r * g.y + be.y) * w.y +
         ((x.z - mean) * r * g.z + be.z) * w.z +
         ((x.w - mean) * r * g.w + be.w) * w.w;
  btree<1>(sm, d);
  if (t == 0) scal[0] = d[0] + bp[0];
}

// ------- enc_w: embed + LN1 -> latent (bf16); n==0 -> latent[:,0] (f32 out) -------
__global__ __launch_bounds__(256) void enc_w(
    const float* __restrict__ expr, const int* __restrict__ idx,
    const float* __restrict__ pos, const float* __restrict__ cls,
    const float* __restrict__ wenc, const float* __restrict__ benc,
    const float* __restrict__ g1, const float* __restrict__ be1,
    const int* __restrict__ keep, unsigned short* __restrict__ latent,
    float* __restrict__ out_l0) {
  __shared__ float sm[512];
  const int bx = blockIdx.x;
  const int b = bx / 501, n = bx % 501;
  const int t = threadIdx.x;
  float4 x;
  int m = 0;
  if (n == 0) {
    float4 c = ((const float4*)cls)[t];
    float4 p = ((const float4*)pos)[t];  // pos row 0
    x.x = c.x + p.x; x.y = c.y + p.y; x.z = c.z + p.z; x.w = c.w + p.w;
  } else {
    m = b * 500 + n - 1;
    const int i = keep[m];
    const float e = expr[b * 2000 + i];
    const int row = idx[b * 2000 + i];
    float4 w = ((const float4*)wenc)[t];
    float4 bb = ((const float4*)benc)[t];
    float4 p = ((const float4*)(pos + (size_t)row * 1024))[t];
    x.x = fmaf(e, w.x, bb.x) + p.x;
    x.y = fmaf(e, w.y, bb.y) + p.y;
    x.z = fmaf(e, w.z, bb.z) + p.z;
    x.w = fmaf(e, w.w, bb.w) + p.w;
  }
  float v[2];
  v[0] = x.x + x.y + x.z + x.w;
  v[1] = x.x * x.x + x.y * x.y + x.z * x.z + x.w * x.w;
  btree<2>(sm, v);
  const float mean = v[0] * (1.f / 1024.f);
  const float r = rsqrtf(v[1] * (1.f / 1024.f) - mean * mean + 1e-5f);
  float4 g = ((const float4*)g1)[t];
  float4 be = ((const float4*)be1)[t];
  const float y0 = (x.x - mean) * r * g.x + be.x;
  const float y1 = (x.y - mean) * r * g.y + be.y;
  const float y2 = (x.z - mean) * r * g.z + be.z;
  const float y3 = (x.w - mean) * r * g.w + be.w;
  if (n == 0) {
    float* o = out_l0 + b * 1024 + t * 4;  // odd f32 offset: scalar stores
    o[0] = y0; o[1] = y1; o[2] = y2; o[3] = y3;
  } else {
    us4 o; o.x = f2bf(y0); o.y = f2bf(y1); o.z = f2bf(y2); o.w = f2bf(y3);
    ((us4*)(latent + (size_t)m * 1024))[t] = o;
  }
}

// ------- gemm_w: Xd = latent @ Bt^T + b_dec (M=16000, N=K=1024, bf16 MFMA) -------
__global__ __launch_bounds__(256, 3) void gemm_w(
    const unsigned short* __restrict__ A,   // latent [16000][1024] bf16
    const unsigned short* __restrict__ Bt,  // [1024 n][1024 k] bf16
    const float* __restrict__ bdec,
    unsigned short* __restrict__ Xd) {
  __shared__ alignas(16) char lds[16384];
  const int tid = threadIdx.x;
  const int wid = tid >> 6;
  const int lane = tid & 63;
  const int bm = blockIdx.x;  // 125
  const int bn = blockIdx.y;  // 8
  const int wm = wid >> 1, wn = wid & 1;

  const int srow = tid >> 2;
  const int g = (tid & 3) ^ ((tid >> 3) & 3);
  const unsigned short* aS = A + (size_t)(bm * 128 + srow) * 1024 + g * 8;
  const unsigned short* bS = Bt + (size_t)(bn * 128 + srow) * 1024 + g * 8;
  char* ldsA = lds;
  char* ldsB = lds + 8192;
  char* stA = ldsA + wid * 1024;  // wave-uniform base; HW adds lane*16
  char* stB = ldsB + wid * 1024;

  f32x4 acc[4][4];
#pragma unroll
  for (int i = 0; i < 4; ++i)
#pragma unroll
    for (int j = 0; j < 4; ++j) { f32x4 z = {0.f, 0.f, 0.f, 0.f}; acc[i][j] = z; }

  const int r = lane & 15;
  const int gg = lane >> 4;
  const int swz = ((gg ^ ((r >> 1) & 3)) * 16);
  const int aRd = (wm * 64 + r) * 64 + swz;
  const int bRd = (wn * 64 + r) * 64 + swz;

  for (int ks = 0; ks < 1024; ks += 32) {
    __builtin_amdgcn_global_load_lds((gas)(aS + ks), (las)(stA), 16, 0, 0);
    __builtin_amdgcn_global_load_lds((gas)(aS + 64 * 1024 + ks), (las)(stA + 4096), 16, 0, 0);
    __builtin_amdgcn_global_load_lds((gas)(bS + ks), (las)(stB), 16, 0, 0);
    __builtin_amdgcn_global_load_lds((gas)(bS + 64 * 1024 + ks), (las)(stB + 4096), 16, 0, 0);
    __syncthreads();
    bf16x8 af[4], bfr[4];
#pragma unroll
    for (int mf = 0; mf < 4; ++mf) af[mf] = *(const bf16x8*)(ldsA + aRd + mf * 1024);
#pragma unroll
    for (int nf = 0; nf < 4; ++nf) bfr[nf] = *(const bf16x8*)(ldsB + bRd + nf * 1024);
#pragma unroll
    for (int mf = 0; mf < 4; ++mf)
#pragma unroll
      for (int nf = 0; nf < 4; ++nf)
        acc[mf][nf] = __builtin_amdgcn_mfma_f32_16x16x32_bf16(af[mf], bfr[nf], acc[mf][nf], 0, 0, 0);
    __syncthreads();
  }
  const int dr = lane >> 4, dc = lane & 15;
#pragma unroll
  for (int nf = 0; nf < 4; ++nf) {
    const int col = bn * 128 + wn * 64 + nf * 16 + dc;
    const float bias = bdec[col];
#pragma unroll
    for (int mf = 0; mf < 4; ++mf) {
      const size_t rbase = (size_t)(bm * 128 + wm * 64 + mf * 16 + dr * 4) * 1024 + col;
      f32x4 v = acc[mf][nf];
#pragma unroll
      for (int q = 0; q < 4; ++q) Xd[rbase + (size_t)q * 1024] = f2bf(v[q] + bias);
    }
  }
}

// ------- pred_w: per kept row: LN2 + dot(W_pred) -> f32 out -------
__global__ __launch_bounds__(256) void pred_w(
    const unsigned short* __restrict__ Xd, const float* __restrict__ g2,
    const float* __restrict__ be2, const float* __restrict__ Wp,
    const float* __restrict__ bp, const int* __restrict__ keep,
    float* __restrict__ out_pred) {
  __shared__ float sm[512];
  const int m = blockIdx.x;
  const int b = m / 500;
  const int t = threadIdx.x;
  us4 xu = ((const us4*)(Xd + (size_t)m * 1024))[t];
  const float x0 = bf2f(xu.x), x1 = bf2f(xu.y), x2 = bf2f(xu.z), x3 = bf2f(xu.w);
  float v[2];
  v[0] = x0 + x1 + x2 + x3;
  v[1] = x0 * x0 + x1 * x1 + x2 * x2 + x3 * x3;
  btree<2>(sm, v);
  const float mean = v[0] * (1.f / 1024.f);
  const float r = rsqrtf(v[1] * (1.f / 1024.f) - mean * mean + 1e-5f);
  float4 g = ((const float4*)g2)[t];
  float4 be = ((const float4*)be2)[t];
  float4 w = ((const float4*)Wp)[t];
  float d[1];
  d[0] = ((x0 - mean) * r * g.x + be.x) * w.x +
         ((x1 - mean) * r * g.y + be.y) * w.y +
         ((x2 - mean) * r * g.z + be.z) * w.z +
         ((x3 - mean) * r * g.w + be.w) * w.w;
  btree<1>(sm, d);
  if (t == 0) {
    const int i = keep[m];
    out_pred[b * 2000 + i] = d[0] + bp[0];
  }
}

// ------- mask_w: mask out (f32), masked pred fill (f32), loss partials -------
__global__ __launch_bounds__(256) void mask_w(
    const int* __restrict__ rank, const float* __restrict__ expr,
    const float* __restrict__ scal, float* __restrict__ out_mask,
    float* __restrict__ out_pred, float* __restrict__ partial) {
  __shared__ float sm[256];
  const int t = blockIdx.x * 256 + threadIdx.x;  // < 64000
  const float pm = scal[0];
  const bool msk = rank[t] >= 500;
  out_mask[t] = msk ? 1.0f : 0.0f;
  float c[1] = {0.f};
  if (msk) {
    out_pred[t] = pm;
    float tv = expr[t];
    if (isnan(tv)) tv = 0.f;
    const float d = pm - tv;
    c[0] = d * d;
  }
  btree<1>(sm, c);
  if (threadIdx.x == 0) partial[blockIdx.x] = c[0];
}

// ------- fin_w: deterministic final loss over 250 partials (f32 out) -------
__global__ __launch_bounds__(256) void fin_w(const float* __restrict__ partial,
                                             float* __restrict__ out) {
  __shared__ float sm[256];
  const int t = threadIdx.x;
  float v[1];
  v[0] = (t < 250) ? partial[t] : 0.f;
  btree<1>(sm, v);
  if (t == 0) out[0] = v[0] * (1.f / 48000.f);
}

extern "C" void kernel_launch(void* const* d_in, const int* in_sizes, int n_in,
                              void* d_out, int out_size, void* d_ws, size_t ws_size,
                              hipStream_t stream) {
  const float* expr = (const float*)d_in[0];
  const int* idx = (const int*)d_in[1];
  const float* noise = (const float*)d_in[2];
  const float* pos = (const float*)d_in[3];
  const float* cls = (const float*)d_in[4];
  const float* wenc = (const float*)d_in[5];
  const float* benc = (const float*)d_in[6];
  const float* g1 = (const float*)d_in[7];
  const float* be1 = (const float*)d_in[8];
  const float* Wdec = (const float*)d_in[9];
  const float* bdec = (const float*)d_in[10];
  const float* mtok = (const float*)d_in[11];
  const float* g2 = (const float*)d_in[12];
  const float* be2 = (const float*)d_in[13];
  const float* Wp = (const float*)d_in[14];
  const float* bp = (const float*)d_in[15];
  float* out = (float*)d_out;  // reference outputs are float32

  char* ws = (char*)d_ws;
  int* rank = (int*)ws;                                  // 32*2000 int
  int* keep = (int*)(ws + 256000);                       // 16000 int
  float* scal = (float*)(ws + 320000);                   // [pred_mask]
  float* partial = (float*)(ws + 320064);                // 250 floats
  unsigned short* Bt = (unsigned short*)(ws + 321536);   // 1024*1024 bf16
  unsigned short* latent = (unsigned short*)(ws + 321536 + 2097152);  // 16000*1024 bf16
  unsigned short* Xd = (unsigned short*)(ws + 321536 + 2097152 + 32768000);
  if (ws_size < (size_t)(321536 + 2097152 + 2 * 32768000)) return;

  // float-unit offsets into d_out: [loss | pred 64000 | mask 64000 | latent0 32768]
  float* out_pred = out + 1;
  float* out_mask = out + 64001;
  float* out_l0 = out + 128001;

  rank_w<<<dim3(32, 4), 512, 0, stream>>>(noise, rank, keep);
  trans_w<<<dim3(32, 32), 256, 0, stream>>>(Wdec, Bt);
  pre_w<<<1, 256, 0, stream>>>(mtok, g2, be2, Wp, bp, scal);
  enc_w<<<32 * 501, 256, 0, stream>>>(expr, idx, pos, cls, wenc, benc, g1, be1,
                                      keep, latent, out_l0);
  gemm_w<<<dim3(125, 8), 256, 0, stream>>>(latent, Bt, bdec, Xd);
  pred_w<<<16000, 256, 0, stream>>>(Xd, g2, be2, Wp, bp, keep, out_pred);
  mask_w<<<250, 256, 0, stream>>>(rank, expr, scal, out_mask, out_pred, partial);
  fin_w<<<1, 256, 0, stream>>>(partial, out);
}

// Round 12
// 218.697 us; speedup vs baseline: 1.1832x; 1.1832x over previous
//
// ===== MaskedAutoencoderViT v12 — rank occupancy fix =====
// v11 passed (258.8 µs). Profile: rank_w 64.7 µs top dispatch, Occupancy
// 10.3%, VALUBusy 18.6% -> latency-bound at 1 wave/SIMD. Split each rank
// into 4 j-quarter partials (grid 32x32, 256 thr) to quadruple occupancy
// and quarter the serial LDS-read chain.
#include <hip/hip_runtime.h>

typedef __attribute__((ext_vector_type(8))) __bf16 bf16x8;
typedef __attribute__((ext_vector_type(4))) float f32x4;
typedef __attribute__((ext_vector_type(4))) unsigned short us4;

typedef const __attribute__((address_space(1))) void* gas;
typedef __attribute__((address_space(3))) void* las;

static __device__ __forceinline__ unsigned short f2bf(float f) {
  unsigned int u = __float_as_uint(f);
  u += 0x7fffu + ((u >> 16) & 1u);
  return (unsigned short)(u >> 16);
}
static __device__ __forceinline__ float bf2f(unsigned short s) {
  return __uint_as_float(((unsigned int)s) << 16);
}

template <int Q>
__device__ __forceinline__ void btree(float* sm, float* v) {
  const int t = threadIdx.x;
#pragma unroll
  for (int q = 0; q < Q; ++q) sm[q * 256 + t] = v[q];
  __syncthreads();
  for (int o = 128; o > 0; o >>= 1) {
    if (t < o)
#pragma unroll
      for (int q = 0; q < Q; ++q) sm[q * 256 + t] += sm[q * 256 + t + o];
    __syncthreads();
  }
#pragma unroll
  for (int q = 0; q < Q; ++q) v[q] = sm[q * 256];
  __syncthreads();
}

// ---- rank_w: stable-sort rank; thread = (i, j-quarter), 4-way LDS combine ----
__global__ __launch_bounds__(256) void rank_w(const float* __restrict__ noise,
                                              int* __restrict__ rank,
                                              int* __restrict__ keep) {
  __shared__ alignas(16) float nz[2000];
  __shared__ int pc[256];
  const int b = blockIdx.x;        // 32 rows
  const int tile = blockIdx.y;     // 32 i-tiles of 64
  const int tid = threadIdx.x;
  const float* nr = noise + b * 2000;
  for (int j = tid; j < 500; j += 256)
    ((float4*)nz)[j] = ((const float4*)nr)[j];
  __syncthreads();
  const int il = tid >> 2;         // 0..63
  const int jq = tid & 3;          // j-quarter
  const int i = tile * 64 + il;
  int cnt = 0;
  if (i < 2000) {
    const float ni = nz[i];
    const int j0 = jq * 125;
#pragma unroll 5
    for (int j4 = j0; j4 < j0 + 125; ++j4) {
      float4 v = ((const float4*)nz)[j4];
      const int j = j4 * 4;
      cnt += (int)((v.x < ni) | ((v.x == ni) & (j < i)));
      cnt += (int)((v.y < ni) | ((v.y == ni) & ((j + 1) < i)));
      cnt += (int)((v.z < ni) | ((v.z == ni) & ((j + 2) < i)));
      cnt += (int)((v.w < ni) | ((v.w == ni) & ((j + 3) < i)));
    }
  }
  pc[tid] = cnt;
  __syncthreads();
  if (jq == 0 && i < 2000) {
    const int total = pc[tid] + pc[tid + 1] + pc[tid + 2] + pc[tid + 3];
    rank[b * 2000 + i] = total;
    if (total < 500) keep[b * 500 + total] = i;  // dense row index = rank
  }
}

// ---------------- trans_w: W_dec (K x N) -> Bt (N x K) bf16 ----------------
__global__ __launch_bounds__(256) void trans_w(const float* __restrict__ W,
                                               unsigned short* __restrict__ Bt) {
  __shared__ float tile[32][33];
  const int tx = threadIdx.x & 31, ty = threadIdx.x >> 5;  // 32x8
  const int r0 = blockIdx.y * 32, c0 = blockIdx.x * 32;
#pragma unroll
  for (int k = 0; k < 4; ++k)
    tile[ty + k * 8][tx] = W[(size_t)(r0 + ty + k * 8) * 1024 + c0 + tx];
  __syncthreads();
#pragma unroll
  for (int k = 0; k < 4; ++k) {
    const int cr = ty + k * 8;
    Bt[(size_t)(c0 + cr) * 1024 + r0 + tx] = f2bf(tile[tx][cr]);
  }
}

// ------- pre_w: pred_mask = W_pred . LN2(mask_token) + b_pred -------
__global__ __launch_bounds__(256) void pre_w(const float* __restrict__ mtok,
                                             const float* __restrict__ g2,
                                             const float* __restrict__ be2,
                                             const float* __restrict__ Wp,
                                             const float* __restrict__ bp,
                                             float* __restrict__ scal) {
  __shared__ float sm[512];
  const int t = threadIdx.x;
  float4 x = ((const float4*)mtok)[t];
  float v[2];
  v[0] = x.x + x.y + x.z + x.w;
  v[1] = x.x * x.x + x.y * x.y + x.z * x.z + x.w * x.w;
  btree<2>(sm, v);
  const float mean = v[0] * (1.f / 1024.f);
  const float r = rsqrtf(v[1] * (1.f / 1024.f) - mean * mean + 1e-5f);
  float4 g = ((const float4*)g2)[t];
  float4 be = ((const float4*)be2)[t];
  float4 w = ((const float4*)Wp)[t];
  float d[1];
  d[0] = ((x.x - mean) * r * g.x + be.x) * w.x +
         ((x.y - mean) * r * g.y + be.y) * w.y +
         ((x.z - mean) * r * g.z + be.z) * w.z +
         ((x.w - mean) * r * g.w + be.w) * w.w;
  btree<1>(sm, d);
  if (t == 0) scal[0] = d[0] + bp[0];
}

// ------- enc_w: embed + LN1 -> latent (bf16); n==0 -> latent[:,0] (f32 out) -------
__global__ __launch_bounds__(256) void enc_w(
    const float* __restrict__ expr, const int* __restrict__ idx,
    const float* __restrict__ pos, const float* __restrict__ cls,
    const float* __restrict__ wenc, const float* __restrict__ benc,
    const float* __restrict__ g1, const float* __restrict__ be1,
    const int* __restrict__ keep, unsigned short* __restrict__ latent,
    float* __restrict__ out_l0) {
  __shared__ float sm[512];
  const int bx = blockIdx.x;
  const int b = bx / 501, n = bx % 501;
  const int t = threadIdx.x;
  float4 x;
  int m = 0;
  if (n == 0) {
    float4 c = ((const float4*)cls)[t];
    float4 p = ((const float4*)pos)[t];  // pos row 0
    x.x = c.x + p.x; x.y = c.y + p.y; x.z = c.z + p.z; x.w = c.w + p.w;
  } else {
    m = b * 500 + n - 1;
    const int i = keep[m];
    const float e = expr[b * 2000 + i];
    const int row = idx[b * 2000 + i];
    float4 w = ((const float4*)wenc)[t];
    float4 bb = ((const float4*)benc)[t];
    float4 p = ((const float4*)(pos + (size_t)row * 1024))[t];
    x.x = fmaf(e, w.x, bb.x) + p.x;
    x.y = fmaf(e, w.y, bb.y) + p.y;
    x.z = fmaf(e, w.z, bb.z) + p.z;
    x.w = fmaf(e, w.w, bb.w) + p.w;
  }
  float v[2];
  v[0] = x.x + x.y + x.z + x.w;
  v[1] = x.x * x.x + x.y * x.y + x.z * x.z + x.w * x.w;
  btree<2>(sm, v);
  const float mean = v[0] * (1.f / 1024.f);
  const float r = rsqrtf(v[1] * (1.f / 1024.f) - mean * mean + 1e-5f);
  float4 g = ((const float4*)g1)[t];
  float4 be = ((const float4*)be1)[t];
  const float y0 = (x.x - mean) * r * g.x + be.x;
  const float y1 = (x.y - mean) * r * g.y + be.y;
  const float y2 = (x.z - mean) * r * g.z + be.z;
  const float y3 = (x.w - mean) * r * g.w + be.w;
  if (n == 0) {
    float* o = out_l0 + b * 1024 + t * 4;  // odd f32 offset: scalar stores
    o[0] = y0; o[1] = y1; o[2] = y2; o[3] = y3;
  } else {
    us4 o; o.x = f2bf(y0); o.y = f2bf(y1); o.z = f2bf(y2); o.w = f2bf(y3);
    ((us4*)(latent + (size_t)m * 1024))[t] = o;
  }
}

// ------- gemm_w: Xd = latent @ Bt^T + b_dec (M=16000, N=K=1024, bf16 MFMA) -------
__global__ __launch_bounds__(256, 3) void gemm_w(
    const unsigned short* __restrict__ A,   // latent [16000][1024] bf16
    const unsigned short* __restrict__ Bt,  // [1024 n][1024 k] bf16
    const float* __restrict__ bdec,
    unsigned short* __restrict__ Xd) {
  __shared__ alignas(16) char lds[16384];
  const int tid = threadIdx.x;
  const int wid = tid >> 6;
  const int lane = tid & 63;
  const int bm = blockIdx.x;  // 125
  const int bn = blockIdx.y;  // 8
  const int wm = wid >> 1, wn = wid & 1;

  const int srow = tid >> 2;
  const int g = (tid & 3) ^ ((tid >> 3) & 3);
  const unsigned short* aS = A + (size_t)(bm * 128 + srow) * 1024 + g * 8;
  const unsigned short* bS = Bt + (size_t)(bn * 128 + srow) * 1024 + g * 8;
  char* ldsA = lds;
  char* ldsB = lds + 8192;
  char* stA = ldsA + wid * 1024;  // wave-uniform base; HW adds lane*16
  char* stB = ldsB + wid * 1024;

  f32x4 acc[4][4];
#pragma unroll
  for (int i = 0; i < 4; ++i)
#pragma unroll
    for (int j = 0; j < 4; ++j) { f32x4 z = {0.f, 0.f, 0.f, 0.f}; acc[i][j] = z; }

  const int r = lane & 15;
  const int gg = lane >> 4;
  const int swz = ((gg ^ ((r >> 1) & 3)) * 16);
  const int aRd = (wm * 64 + r) * 64 + swz;
  const int bRd = (wn * 64 + r) * 64 + swz;

  for (int ks = 0; ks < 1024; ks += 32) {
    __builtin_amdgcn_global_load_lds((gas)(aS + ks), (las)(stA), 16, 0, 0);
    __builtin_amdgcn_global_load_lds((gas)(aS + 64 * 1024 + ks), (las)(stA + 4096), 16, 0, 0);
    __builtin_amdgcn_global_load_lds((gas)(bS + ks), (las)(stB), 16, 0, 0);
    __builtin_amdgcn_global_load_lds((gas)(bS + 64 * 1024 + ks), (las)(stB + 4096), 16, 0, 0);
    __syncthreads();
    bf16x8 af[4], bfr[4];
#pragma unroll
    for (int mf = 0; mf < 4; ++mf) af[mf] = *(const bf16x8*)(ldsA + aRd + mf * 1024);
#pragma unroll
    for (int nf = 0; nf < 4; ++nf) bfr[nf] = *(const bf16x8*)(ldsB + bRd + nf * 1024);
#pragma unroll
    for (int mf = 0; mf < 4; ++mf)
#pragma unroll
      for (int nf = 0; nf < 4; ++nf)
        acc[mf][nf] = __builtin_amdgcn_mfma_f32_16x16x32_bf16(af[mf], bfr[nf], acc[mf][nf], 0, 0, 0);
    __syncthreads();
  }
  const int dr = lane >> 4, dc = lane & 15;
#pragma unroll
  for (int nf = 0; nf < 4; ++nf) {
    const int col = bn * 128 + wn * 64 + nf * 16 + dc;
    const float bias = bdec[col];
#pragma unroll
    for (int mf = 0; mf < 4; ++mf) {
      const size_t rbase = (size_t)(bm * 128 + wm * 64 + mf * 16 + dr * 4) * 1024 + col;
      f32x4 v = acc[mf][nf];
#pragma unroll
      for (int q = 0; q < 4; ++q) Xd[rbase + (size_t)q * 1024] = f2bf(v[q] + bias);
    }
  }
}

// ------- pred_w: per kept row: LN2 + dot(W_pred) -> f32 out -------
__global__ __launch_bounds__(256) void pred_w(
    const unsigned short* __restrict__ Xd, const float* __restrict__ g2,
    const float* __restrict__ be2, const float* __restrict__ Wp,
    const float* __restrict__ bp, const int* __restrict__ keep,
    float* __restrict__ out_pred) {
  __shared__ float sm[512];
  const int m = blockIdx.x;
  const int b = m / 500;
  const int t = threadIdx.x;
  us4 xu = ((const us4*)(Xd + (size_t)m * 1024))[t];
  const float x0 = bf2f(xu.x), x1 = bf2f(xu.y), x2 = bf2f(xu.z), x3 = bf2f(xu.w);
  float v[2];
  v[0] = x0 + x1 + x2 + x3;
  v[1] = x0 * x0 + x1 * x1 + x2 * x2 + x3 * x3;
  btree<2>(sm, v);
  const float mean = v[0] * (1.f / 1024.f);
  const float r = rsqrtf(v[1] * (1.f / 1024.f) - mean * mean + 1e-5f);
  float4 g = ((const float4*)g2)[t];
  float4 be = ((const float4*)be2)[t];
  float4 w = ((const float4*)Wp)[t];
  float d[1];
  d[0] = ((x0 - mean) * r * g.x + be.x) * w.x +
         ((x1 - mean) * r * g.y + be.y) * w.y +
         ((x2 - mean) * r * g.z + be.z) * w.z +
         ((x3 - mean) * r * g.w + be.w) * w.w;
  btree<1>(sm, d);
  if (t == 0) {
    const int i = keep[m];
    out_pred[b * 2000 + i] = d[0] + bp[0];
  }
}

// ------- mask_w: mask out (f32), masked pred fill (f32), loss partials -------
__global__ __launch_bounds__(256) void mask_w(
    const int* __restrict__ rank, const float* __restrict__ expr,
    const float* __restrict__ scal, float* __restrict__ out_mask,
    float* __restrict__ out_pred, float* __restrict__ partial) {
  __shared__ float sm[256];
  const int t = blockIdx.x * 256 + threadIdx.x;  // < 64000
  const float pm = scal[0];
  const bool msk = rank[t] >= 500;
  out_mask[t] = msk ? 1.0f : 0.0f;
  float c[1] = {0.f};
  if (msk) {
    out_pred[t] = pm;
    float tv = expr[t];
    if (isnan(tv)) tv = 0.f;
    const float d = pm - tv;
    c[0] = d * d;
  }
  btree<1>(sm, c);
  if (threadIdx.x == 0) partial[blockIdx.x] = c[0];
}

// ------- fin_w: deterministic final loss over 250 partials (f32 out) -------
__global__ __launch_bounds__(256) void fin_w(const float* __restrict__ partial,
                                             float* __restrict__ out) {
  __shared__ float sm[256];
  const int t = threadIdx.x;
  float v[1];
  v[0] = (t < 250) ? partial[t] : 0.f;
  btree<1>(sm, v);
  if (t == 0) out[0] = v[0] * (1.f / 48000.f);
}

extern "C" void kernel_launch(void* const* d_in, const int* in_sizes, int n_in,
                              void* d_out, int out_size, void* d_ws, size_t ws_size,
                              hipStream_t stream) {
  const float* expr = (const float*)d_in[0];
  const int* idx = (const int*)d_in[1];
  const float* noise = (const float*)d_in[2];
  const float* pos = (const float*)d_in[3];
  const float* cls = (const float*)d_in[4];
  const float* wenc = (const float*)d_in[5];
  const float* benc = (const float*)d_in[6];
  const float* g1 = (const float*)d_in[7];
  const float* be1 = (const float*)d_in[8];
  const float* Wdec = (const float*)d_in[9];
  const float* bdec = (const float*)d_in[10];
  const float* mtok = (const float*)d_in[11];
  const float* g2 = (const float*)d_in[12];
  const float* be2 = (const float*)d_in[13];
  const float* Wp = (const float*)d_in[14];
  const float* bp = (const float*)d_in[15];
  float* out = (float*)d_out;  // reference outputs are float32

  char* ws = (char*)d_ws;
  int* rank = (int*)ws;                                  // 32*2000 int
  int* keep = (int*)(ws + 256000);                       // 16000 int
  float* scal = (float*)(ws + 320000);                   // [pred_mask]
  float* partial = (float*)(ws + 320064);                // 250 floats
  unsigned short* Bt = (unsigned short*)(ws + 321536);   // 1024*1024 bf16
  unsigned short* latent = (unsigned short*)(ws + 321536 + 2097152);  // 16000*1024 bf16
  unsigned short* Xd = (unsigned short*)(ws + 321536 + 2097152 + 32768000);
  if (ws_size < (size_t)(321536 + 2097152 + 2 * 32768000)) return;

  // float-unit offsets into d_out: [loss | pred 64000 | mask 64000 | latent0 32768]
  float* out_pred = out + 1;
  float* out_mask = out + 64001;
  float* out_l0 = out + 128001;

  rank_w<<<dim3(32, 32), 256, 0, stream>>>(noise, rank, keep);
  trans_w<<<dim3(32, 32), 256, 0, stream>>>(Wdec, Bt);
  pre_w<<<1, 256, 0, stream>>>(mtok, g2, be2, Wp, bp, scal);
  enc_w<<<32 * 501, 256, 0, stream>>>(expr, idx, pos, cls, wenc, benc, g1, be1,
                                      keep, latent, out_l0);
  gemm_w<<<dim3(125, 8), 256, 0, stream>>>(latent, Bt, bdec, Xd);
  pred_w<<<16000, 256, 0, stream>>>(Xd, g2, be2, Wp, bp, keep, out_pred);
  mask_w<<<250, 256, 0, stream>>>(rank, expr, scal, out_mask, out_pred, partial);
  fin_w<<<1, 256, 0, stream>>>(partial, out);
}